// Round 1
// 169.824 us; speedup vs baseline: 1.1781x; 1.1781x over previous
//
#include <hip/hip_runtime.h>
#include <hip/hip_bf16.h>
#include <math.h>

// Problem shape (fixed by setup_inputs):
//   x: [2, 64, 192, 192] fp32, scale=scale2=2 -> sh=sw=384, out: [2,64,384,384] fp32
#define BN  2
#define CN  64
#define HN  192
#define WN  192
#define SH  384
#define SW  384
#define HW  (HN * WN)
#define NPIX (BN * HN * WN)   // 73728

typedef __attribute__((ext_vector_type(8))) short bf16x8;
typedef __attribute__((ext_vector_type(4))) float f32x4;

#define KPAD 200   // bf16 elems per n-row of LDS B tile (192 + 8 pad -> conflict-free b128 reads)

// exact round-to-nearest-even fp32 -> bf16 bits
__device__ inline unsigned short f2bf(float f) {
    unsigned int u = __float_as_uint(f);
    u += 0x7fffu + ((u >> 16) & 1u);
    return (unsigned short)(u >> 16);
}

// One column's sobel via the proven shuffle + wave-uniform-halo idiom.
__device__ inline void sobel_col(const float* __restrict__ xc,
    size_t oT, size_t oM, size_t oB, int j, int jL, int jR,
    float mt, float mb, float mLt, float mLm, float mLb,
    float mRt, float mRm, float mRb, bool isL, bool isR,
    float& m_out, float& sx, float& sy)
{
    float t   = xc[oT + j] * mt;
    float m   = xc[oM + j];
    float btm = xc[oB + j] * mb;
    float hLt = xc[oT + jL] * mLt;
    float hLm = xc[oM + jL] * mLm;
    float hLb = xc[oB + jL] * mLb;
    float hRt = xc[oT + jR] * mRt;
    float hRm = xc[oM + jR] * mRm;
    float hRb = xc[oB + jR] * mRb;
    float tl  = __shfl_up(t, 1),   ml_ = __shfl_up(m, 1),   bl_ = __shfl_up(btm, 1);
    float tr  = __shfl_down(t, 1), mr_ = __shfl_down(m, 1), br_ = __shfl_down(btm, 1);
    float n0 = isL ? hLt : tl;
    float n3 = isL ? hLm : ml_;
    float n6 = isL ? hLb : bl_;
    float n2 = isR ? hRt : tr;
    float n5 = isR ? hRm : mr_;
    float n8 = isR ? hRb : br_;
    m_out = m;
    sx = (n2 - n0) + 2.f * (n5 - n3) + (n8 - n6);
    sy = (n6 - n0) + 2.f * (btm - t) + (n8 - n2);
}

// ---------------------------------------------------------------------------
// Kernel 1 (v6): feat via bf16 MFMA GEMM.
// Block = 256 threads = 4 waves; tile = (batch b, row i, 64 cols) x all 64 out ch.
// Stage: wave w computes m/sx/sy for channels [16w,16w+16) over the 64 cols
// (ONCE per pixel, vs 4x in v5), converts to bf16, writes Bs[n][k] (k = c /
// 64+c / 128+c). A (weights) -> bf16 register fragments, loaded once.
// Compute: 24 x mfma_f32_16x16x32_bf16 per wave (4 N-subtiles x 6 K-steps).
// D layout (m89-verified): col = lane&15, row = (lane>>4)*4 + reg.
// KPAD=200: b128 B-frag reads are bank-conflict-free (8 lanes / 4-bank group).
// ---------------------------------------------------------------------------
__global__ __launch_bounds__(256) void feat_kernel(
    const float* __restrict__ x,     // [B,64,H,W]
    const float* __restrict__ wcv,   // [64,192]
    const float* __restrict__ bcv,   // [64]
    float* __restrict__ feat)        // [B,64,H,W]
{
    __shared__ unsigned short Bs[64 * KPAD];   // 25.6 KB, [n=col][k] bf16 bits

    int bi = blockIdx.x;                 // 2*192*3 = 1152 blocks
    int jt = bi % 3;
    int t2 = bi / 3;
    int i  = t2 % HN;
    int b  = t2 / HN;
    int j0 = jt * 64;                    // naturally wave-uniform (SGPR)

    int tid  = threadIdx.x;
    int w    = __builtin_amdgcn_readfirstlane(tid >> 6);   // wave id 0..3
    int lane = tid & 63;

    // ---- A fragments: out-channels [16w,16w+16), all 192 K, bf16 in regs ----
    int mrow = (w << 4) + (lane & 15);
    int kb   = (lane >> 4) << 3;         // 0,8,16,24
    bf16x8 afrag[6];
    {
        const float* wr_ = wcv + mrow * 192 + kb;
#pragma unroll
        for (int ks = 0; ks < 6; ++ks) {
            float4 lo = *(const float4*)(wr_ + ks * 32);
            float4 hi = *(const float4*)(wr_ + ks * 32 + 4);
            bf16x8 a;
            a[0] = (short)f2bf(lo.x); a[1] = (short)f2bf(lo.y);
            a[2] = (short)f2bf(lo.z); a[3] = (short)f2bf(lo.w);
            a[4] = (short)f2bf(hi.x); a[5] = (short)f2bf(hi.y);
            a[6] = (short)f2bf(hi.z); a[7] = (short)f2bf(hi.w);
            afrag[ks] = a;
        }
    }

    // ---- Stage X' = [x; sobel_x; sobel_y] tile into LDS as bf16 ----
    bool ok_t = (i > 0), ok_b = (i < HN - 1);
    bool okL = (j0 > 0), okR = (j0 + 64 < WN);
    float mt = ok_t ? 1.f : 0.f, mb = ok_b ? 1.f : 0.f;
    int rT = ok_t ? i - 1 : i;
    int rB = ok_b ? i + 1 : i;
    int jL = okL ? j0 - 1 : j0;
    int jR = okR ? j0 + 64 : j0;
    float mLt = okL ? mt : 0.f, mLm = okL ? 1.f : 0.f, mLb = okL ? mb : 0.f;
    float mRt = okR ? mt : 0.f, mRm = okR ? 1.f : 0.f, mRb = okR ? mb : 0.f;
    bool isL = (lane == 0), isR = (lane == 63);

    const float* xb = x + (size_t)b * CN * HW;
    size_t oT = (size_t)rT * WN, oM = (size_t)i * WN, oB = (size_t)rB * WN;
    int j = j0 + lane;

    unsigned short* brow = Bs + lane * KPAD;     // this lane's pixel column
#pragma unroll 2
    for (int cp = 0; cp < 8; ++cp) {
        int c0 = (w << 4) + (cp << 1);           // even channel of the pair
        float m0, sx0, sy0, m1, sx1, sy1;
        sobel_col(xb + (size_t)c0 * HW, oT, oM, oB, j, jL, jR,
                  mt, mb, mLt, mLm, mLb, mRt, mRm, mRb, isL, isR, m0, sx0, sy0);
        sobel_col(xb + (size_t)(c0 + 1) * HW, oT, oM, oB, j, jL, jR,
                  mt, mb, mLt, mLm, mLb, mRt, mRm, mRb, isL, isR, m1, sx1, sy1);
        // paired bf16 writes (4B aligned: c0 even, KPAD*2 % 4 == 0)
        *(unsigned int*)(brow + c0)       = (unsigned int)f2bf(m0)  | ((unsigned int)f2bf(m1)  << 16);
        *(unsigned int*)(brow + 64 + c0)  = (unsigned int)f2bf(sx0) | ((unsigned int)f2bf(sx1) << 16);
        *(unsigned int*)(brow + 128 + c0) = (unsigned int)f2bf(sy0) | ((unsigned int)f2bf(sy1) << 16);
    }

    __syncthreads();

    // ---- MFMA: D[16 x 64] per wave = A[16 x 192] * B[192 x 64] ----
    f32x4 acc[4] = {};
    const unsigned short* bp = Bs + (lane & 15) * KPAD + ((lane >> 4) << 3);
#pragma unroll
    for (int nt = 0; nt < 4; ++nt) {
        const unsigned short* bnt = bp + nt * 16 * KPAD;
#pragma unroll
        for (int ks = 0; ks < 6; ++ks) {
            bf16x8 bf = *(const bf16x8*)(bnt + ks * 32);
            acc[nt] = __builtin_amdgcn_mfma_f32_16x16x32_bf16(afrag[ks], bf, acc[nt], 0, 0, 0);
        }
    }

    // ---- Epilogue: bias + store ----
    int n0 = j0 + (lane & 15);
    int mbase = (w << 4) + ((lane >> 4) << 2);
    size_t outb = (size_t)b * CN * HW + (size_t)i * WN;
#pragma unroll
    for (int rr = 0; rr < 4; ++rr) {
        int m = mbase + rr;
        float bias = bcv[m];
        size_t rowb = outb + (size_t)m * HW + n0;
#pragma unroll
        for (int nt = 0; nt < 4; ++nt)
            feat[rowb + nt * 16] = acc[nt][rr] + bias;
    }
}

// ---------------------------------------------------------------------------
// MLP helper: one wave, lane = hidden unit. Returns head partial sums p[6]
// (full sums present in ALL lanes after butterfly).
// ---------------------------------------------------------------------------
__device__ inline void run_mlp(int lane, float in0, float in1, float chv, float cwv,
    const float* __restrict__ wb1, const float* __restrict__ bb1,
    const float* __restrict__ wb2, const float* __restrict__ bb2,
    const float* __restrict__ wr,  const float* __restrict__ wo, float p[6])
{
    float4 w1 = ((const float4*)wb1)[lane];
    float h1 = fmaxf(bb1[lane] + w1.x * in0 + w1.y * in1 + w1.z * chv + w1.w * cwv, 0.f);
    const float4* w2row = (const float4*)(wb2 + lane * 64);
    float acc = bb2[lane];
#pragma unroll
    for (int q = 0; q < 16; ++q) {
        float4 wv = w2row[q];
        acc += wv.x * __shfl(h1, q * 4 + 0)
             + wv.y * __shfl(h1, q * 4 + 1)
             + wv.z * __shfl(h1, q * 4 + 2)
             + wv.w * __shfl(h1, q * 4 + 3);
    }
    float h2 = fmaxf(acc, 0.f);
#pragma unroll
    for (int e = 0; e < 4; ++e) p[e] = wr[e * 64 + lane] * h2;
#pragma unroll
    for (int e = 0; e < 2; ++e) p[4 + e] = wo[e * 64 + lane] * h2;
#pragma unroll
    for (int m = 1; m < 64; m <<= 1) {
#pragma unroll
        for (int e = 0; e < 6; ++e) p[e] += __shfl_xor(p[e], m);
    }
}

// ---------------------------------------------------------------------------
// Kernel 2 (v4): periodic routing/offset table.
// tblEntry[entry][8] = {re[4], offx, offy, pad, pad}.
// Fast mode (sc2==2, sc<=16): wave pi computes BOTH parity classes and emits
// mixed expert matrices as (avg,diff) pairs at tblMix[pi][2048].
// ---------------------------------------------------------------------------
__global__ __launch_bounds__(256) void mlp_table_kernel(
    const float* __restrict__ wb1, const float* __restrict__ bb1,
    const float* __restrict__ wb2, const float* __restrict__ bb2,
    const float* __restrict__ wr,  const float* __restrict__ br,
    const float* __restrict__ wo,  const float* __restrict__ bo,
    const float* __restrict__ wce, const float* __restrict__ wee,
    const int* __restrict__ scale_p, const int* __restrict__ scale2_p,
    float* __restrict__ tblEntry, float* __restrict__ tblMix)
{
    int sc = scale_p[0], sc2 = scale2_p[0];
    int w = (blockIdx.x * 256 + threadIdx.x) >> 6;
    int lane = threadIdx.x & 63;
    float scale = (float)sc, scale2 = (float)sc2;
    float in0 = 1.f / scale2, in1 = 1.f / scale;
    bool fast = (sc2 == 2 && sc <= 16);

    if (fast) {
        if (w >= sc) return;
        int pi = w;
        float ih = (pi + 0.5f) / scale;
        float chv = ih - floorf(ih + 0.001f) - 0.5f;
        float p0[6], p1[6];
        {
            float iw = 0.5f / scale2;
            float cwv = iw - floorf(iw + 0.001f) - 0.5f;
            run_mlp(lane, in0, in1, chv, cwv, wb1, bb1, wb2, bb2, wr, wo, p0);
        }
        {
            float iw = 1.5f / scale2;
            float cwv = iw - floorf(iw + 0.001f) - 0.5f;
            run_mlp(lane, in0, in1, chv, cwv, wb1, bb1, wb2, bb2, wr, wo, p1);
        }
        float reE[4], reO[4];
#pragma unroll
        for (int e = 0; e < 4; ++e) {
            reE[e] = 1.f / (1.f + expf(-(p0[e] + br[e])));
            reO[e] = 1.f / (1.f + expf(-(p1[e] + br[e])));
        }
        if (lane == 0) {
            float* t0 = tblEntry + (pi * 2 + 0) * 8;
            float* t1 = tblEntry + (pi * 2 + 1) * 8;
#pragma unroll
            for (int e = 0; e < 4; ++e) { t0[e] = reE[e]; t1[e] = reO[e]; }
            t0[4] = p0[4] + bo[0]; t0[5] = p0[5] + bo[1];
            t1[4] = p1[4] + bo[0]; t1[5] = p1[5] + bo[1];
        }
        float* mp = tblMix + pi * 2048;
        for (int idx = lane; idx < 512; idx += 64) {
            float cE = reE[0] * wce[idx]        + reE[1] * wce[512 + idx]
                     + reE[2] * wce[1024 + idx] + reE[3] * wce[1536 + idx];
            float cO = reO[0] * wce[idx]        + reO[1] * wce[512 + idx]
                     + reO[2] * wce[1024 + idx] + reO[3] * wce[1536 + idx];
            mp[idx]       = 0.5f * (cE + cO);
            mp[512 + idx] = 0.5f * (cE - cO);
            float eE = reE[0] * wee[idx]        + reE[1] * wee[512 + idx]
                     + reE[2] * wee[1024 + idx] + reE[3] * wee[1536 + idx];
            float eO = reO[0] * wee[idx]        + reO[1] * wee[512 + idx]
                     + reO[2] * wee[1024 + idx] + reO[3] * wee[1536 + idx];
            mp[1024 + idx] = 0.5f * (eE + eO);
            mp[1536 + idx] = 0.5f * (eE - eO);
        }
    } else {
        if (w >= sc * sc2) return;
        int pi = w / sc2, pj = w - pi * sc2;
        float ih = (pi + 0.5f) / scale;
        float chv = ih - floorf(ih + 0.001f) - 0.5f;
        float iw = (pj + 0.5f) / scale2;
        float cwv = iw - floorf(iw + 0.001f) - 0.5f;
        float p[6];
        run_mlp(lane, in0, in1, chv, cwv, wb1, bb1, wb2, bb2, wr, wo, p);
        if (lane == 0) {
            float* tp = tblEntry + w * 8;
#pragma unroll
            for (int e = 0; e < 4; ++e) tp[e] = 1.f / (1.f + expf(-(p[e] + br[e])));
            tp[4] = p[4] + bo[0];
            tp[5] = p[5] + bo[1];
        }
    }
}

// ---------------------------------------------------------------------------
// Kernel 3 (v3): bilinear gather + expert mix + residual.
// Block = 64 px row segment x 4 waves (wave = 16 channels).
// XCD band swizzle for feat L2 locality. Fast path (sc2==2): wave-uniform
// (avg,diff) mixed weights + per-lane parity sign. Generic path kept.
// ---------------------------------------------------------------------------
__global__ __launch_bounds__(256) void out_kernel(
    const float* __restrict__ feat,      // [B,64,H,W]
    const float* __restrict__ tblEntry,  // [256][8]
    const float* __restrict__ tblMix,    // [16][2048]
    const float* __restrict__ wce,       // [4,8,64]
    const float* __restrict__ wee,       // [4,64,8]
    const int* __restrict__ scale_p, const int* __restrict__ scale2_p,
    float* __restrict__ out)             // [B,64,SH,SW]
{
    __shared__ float midp[4 * 64 * 9];

    int Bk = blockIdx.x;
    int T = gridDim.x;                           // 4608, %8==0
    int t = ((T & 7) == 0) ? ((Bk & 7) * (T >> 3) + (Bk >> 3)) : Bk;

    int tid = threadIdx.x;
    int g = __builtin_amdgcn_readfirstlane(tid >> 6);
    int lane = tid & 63;
    int pix0 = t * 64;
    int b = pix0 / (SH * SW);
    int r0 = pix0 - b * SH * SW;
    int i = r0 / SW;
    int j0 = r0 - i * SW;
    int j = j0 + lane;
    int r = r0 + lane;

    int sc = scale_p[0], sc2 = scale2_p[0];
    float scale = (float)sc, scale2 = (float)sc2;
    int pi = i - (i / sc) * sc;          // wave-uniform
    int pj = j - (j / sc2) * sc2;        // per-lane
    int entry = pi * sc2 + pj;
    float offx = tblEntry[entry * 8 + 4];
    float offy = tblEntry[entry * 8 + 5];

    const float inv_wm1 = 2.f / (float)(WN - 1);
    const float inv_hm1 = 2.f / (float)(HN - 1);
    float gx = ((j + 0.5f) / scale2 - 0.5f) * inv_wm1 - 1.f + offx * inv_wm1;
    float gy = ((i + 0.5f) / scale  - 0.5f) * inv_hm1 - 1.f + offy * inv_hm1;

    float ix = ((gx + 1.f) * WN - 1.f) * 0.5f;
    float iy = ((gy + 1.f) * HN - 1.f) * 0.5f;
    float fx0 = floorf(ix), fy0 = floorf(iy);
    int x0 = (int)fx0, y0 = (int)fy0;
    float wx1 = ix - fx0, wx0 = 1.f - wx1;
    float wy1 = iy - fy0, wy0 = 1.f - wy1;

    bool vx0 = (x0 >= 0) && (x0 <= WN - 1);
    bool vx1 = (x0 + 1 >= 0) && (x0 + 1 <= WN - 1);
    bool vy0 = (y0 >= 0) && (y0 <= HN - 1);
    bool vy1 = (y0 + 1 >= 0) && (y0 + 1 <= HN - 1);
    bool v00 = vx0 && vy0, v10 = vx1 && vy0, v01 = vx0 && vy1, v11 = vx1 && vy1;
    float w00 = wx0 * wy0, w10 = wx1 * wy0, w01 = wx0 * wy1, w11 = wx1 * wy1;

    int i00 = y0 * WN + x0;
    int i10 = i00 + 1;
    int i01 = i00 + WN;
    int i11 = i01 + 1;

    const float* fb = feat + (size_t)b * CN * HW;

    float f0[16];
#pragma unroll
    for (int cc = 0; cc < 16; ++cc) {
        const float* fc = fb + (size_t)(g * 16 + cc) * HW;
        float a  = v00 ? fc[i00] : 0.f;
        float bq = v10 ? fc[i10] : 0.f;
        float cq = v01 ? fc[i01] : 0.f;
        float dq = v11 ? fc[i11] : 0.f;
        f0[cc] = a * w00 + bq * w10 + cq * w01 + dq * w11;
    }

    bool fast = (sc2 == 2 && sc <= 16);
    if (fast) {
        float sgn = (pj == 0) ? 1.f : -1.f;
        const float* mp = tblMix + pi * 2048;    // uniform base -> s_load weights
#pragma unroll
        for (int k = 0; k < 8; ++k) {
            const float* wa = mp + k * 64 + g * 16;
            const float* wd = mp + 512 + k * 64 + g * 16;
            float dA = 0.f, dB = 0.f;
#pragma unroll
            for (int cc = 0; cc < 16; ++cc) { dA += wa[cc] * f0[cc]; dB += wd[cc] * f0[cc]; }
            midp[(g * 64 + lane) * 9 + k] = fmaf(sgn, dB, dA);
        }
        __syncthreads();
        float mid[8];
#pragma unroll
        for (int k = 0; k < 8; ++k)
            mid[k] = midp[(0 * 64 + lane) * 9 + k] + midp[(1 * 64 + lane) * 9 + k]
                   + midp[(2 * 64 + lane) * 9 + k] + midp[(3 * 64 + lane) * 9 + k];
#pragma unroll
        for (int cc = 0; cc < 16; ++cc) {
            int c = g * 16 + cc;
            const float* wa = mp + 1024 + c * 8;
            const float* wd = mp + 1536 + c * 8;
            float vA = 0.f, vB = 0.f;
#pragma unroll
            for (int k = 0; k < 8; ++k) { vA += wa[k] * mid[k]; vB += wd[k] * mid[k]; }
            out[(size_t)(b * CN + c) * SH * SW + r] = f0[cc] + fmaf(sgn, vB, vA);
        }
    } else {
        float4 rw = *(const float4*)(tblEntry + entry * 8);
        float re[4] = {rw.x, rw.y, rw.z, rw.w};
        float part[4][8];
#pragma unroll
        for (int e = 0; e < 4; ++e) {
#pragma unroll
            for (int k = 0; k < 8; ++k) {
                const float* wrow = wce + (e * 8 + k) * 64 + g * 16;
                float d = 0.f;
#pragma unroll
                for (int cc = 0; cc < 16; ++cc) d += wrow[cc] * f0[cc];
                part[e][k] = d;
            }
        }
#pragma unroll
        for (int k = 0; k < 8; ++k) {
            float m = re[0] * part[0][k] + re[1] * part[1][k]
                    + re[2] * part[2][k] + re[3] * part[3][k];
            midp[(g * 64 + lane) * 9 + k] = m;
        }
        __syncthreads();
        float mid[8];
#pragma unroll
        for (int k = 0; k < 8; ++k)
            mid[k] = midp[(0 * 64 + lane) * 9 + k] + midp[(1 * 64 + lane) * 9 + k]
                   + midp[(2 * 64 + lane) * 9 + k] + midp[(3 * 64 + lane) * 9 + k];
#pragma unroll
        for (int cc = 0; cc < 16; ++cc) {
            int c = g * 16 + cc;
            float v = f0[cc];
#pragma unroll
            for (int e = 0; e < 4; ++e) {
                const float* wrow = wee + (e * 64 + c) * 8;
                float d = 0.f;
#pragma unroll
                for (int k = 0; k < 8; ++k) d += wrow[k] * mid[k];
                v += re[e] * d;
            }
            out[(size_t)(b * CN + c) * SH * SW + r] = v;
        }
    }
}

extern "C" void kernel_launch(void* const* d_in, const int* in_sizes, int n_in,
                              void* d_out, int out_size, void* d_ws, size_t ws_size,
                              hipStream_t stream) {
    const float* x    = (const float*)d_in[0];
    const float* wce  = (const float*)d_in[1];
    const float* wee  = (const float*)d_in[2];
    const float* wb1  = (const float*)d_in[3];
    const float* bb1  = (const float*)d_in[4];
    const float* wb2  = (const float*)d_in[5];
    const float* bb2  = (const float*)d_in[6];
    const float* wr   = (const float*)d_in[7];
    const float* br   = (const float*)d_in[8];
    const float* wo   = (const float*)d_in[9];
    const float* bo   = (const float*)d_in[10];
    const float* wcv  = (const float*)d_in[11];
    const float* bcv  = (const float*)d_in[12];
    const int*   scale  = (const int*)d_in[13];
    const int*   scale2 = (const int*)d_in[14];
    float* out = (float*)d_out;

    float* feat     = (float*)d_ws;                       // BN*CN*HW floats
    float* tblEntry = feat + (size_t)BN * CN * HW;        // 256*8 floats
    float* tblMix   = tblEntry + 256 * 8;                 // 16*2048 floats

    feat_kernel<<<BN * HN * 3, 256, 0, stream>>>(x, wcv, bcv, feat);
    mlp_table_kernel<<<64, 256, 0, stream>>>(wb1, bb1, wb2, bb2, wr, br, wo, bo,
                                             wce, wee, scale, scale2,
                                             tblEntry, tblMix);
    out_kernel<<<BN * SH * SW / 64, 256, 0, stream>>>(feat, tblEntry, tblMix,
                                                      wce, wee, scale, scale2, out);
}

// Round 2
// 162.155 us; speedup vs baseline: 1.2338x; 1.0473x over previous
//
#include <hip/hip_runtime.h>
#include <hip/hip_bf16.h>
#include <math.h>

// Problem shape (fixed by setup_inputs):
//   x: [2, 64, 192, 192] fp32, scale=scale2=2 -> sh=sw=384, out: [2,64,384,384] fp32
#define BN  2
#define CN  64
#define HN  192
#define WN  192
#define SH  384
#define SW  384
#define HW  (HN * WN)
#define NPIX (BN * HN * WN)   // 73728

typedef __attribute__((ext_vector_type(8))) short bf16x8;
typedef __attribute__((ext_vector_type(4))) float f32x4;

#define KPAD 200   // bf16 elems per n-row of feat LDS B tile (conflict-free b128 reads)

// exact round-to-nearest-even fp32 -> bf16 bits
__device__ inline unsigned short f2bf(float f) {
    unsigned int u = __float_as_uint(f);
    u += 0x7fffu + ((u >> 16) & 1u);
    return (unsigned short)(u >> 16);
}

// One column's sobel via the proven shuffle + wave-uniform-halo idiom.
__device__ inline void sobel_col(const float* __restrict__ xc,
    size_t oT, size_t oM, size_t oB, int j, int jL, int jR,
    float mt, float mb, float mLt, float mLm, float mLb,
    float mRt, float mRm, float mRb, bool isL, bool isR,
    float& m_out, float& sx, float& sy)
{
    float t   = xc[oT + j] * mt;
    float m   = xc[oM + j];
    float btm = xc[oB + j] * mb;
    float hLt = xc[oT + jL] * mLt;
    float hLm = xc[oM + jL] * mLm;
    float hLb = xc[oB + jL] * mLb;
    float hRt = xc[oT + jR] * mRt;
    float hRm = xc[oM + jR] * mRm;
    float hRb = xc[oB + jR] * mRb;
    float tl  = __shfl_up(t, 1),   ml_ = __shfl_up(m, 1),   bl_ = __shfl_up(btm, 1);
    float tr  = __shfl_down(t, 1), mr_ = __shfl_down(m, 1), br_ = __shfl_down(btm, 1);
    float n0 = isL ? hLt : tl;
    float n3 = isL ? hLm : ml_;
    float n6 = isL ? hLb : bl_;
    float n2 = isR ? hRt : tr;
    float n5 = isR ? hRm : mr_;
    float n8 = isR ? hRb : br_;
    m_out = m;
    sx = (n2 - n0) + 2.f * (n5 - n3) + (n8 - n6);
    sy = (n6 - n0) + 2.f * (btm - t) + (n8 - n2);
}

// ---------------------------------------------------------------------------
// Kernel 1 (v6, unchanged): feat via bf16 MFMA GEMM.
// ---------------------------------------------------------------------------
__global__ __launch_bounds__(256) void feat_kernel(
    const float* __restrict__ x,     // [B,64,H,W]
    const float* __restrict__ wcv,   // [64,192]
    const float* __restrict__ bcv,   // [64]
    float* __restrict__ feat)        // [B,64,H,W]
{
    __shared__ unsigned short Bs[64 * KPAD];   // 25.6 KB, [n=col][k] bf16 bits

    int bi = blockIdx.x;                 // 2*192*3 = 1152 blocks
    int jt = bi % 3;
    int t2 = bi / 3;
    int i  = t2 % HN;
    int b  = t2 / HN;
    int j0 = jt * 64;

    int tid  = threadIdx.x;
    int w    = __builtin_amdgcn_readfirstlane(tid >> 6);
    int lane = tid & 63;

    int mrow = (w << 4) + (lane & 15);
    int kb   = (lane >> 4) << 3;
    bf16x8 afrag[6];
    {
        const float* wr_ = wcv + mrow * 192 + kb;
#pragma unroll
        for (int ks = 0; ks < 6; ++ks) {
            float4 lo = *(const float4*)(wr_ + ks * 32);
            float4 hi = *(const float4*)(wr_ + ks * 32 + 4);
            bf16x8 a;
            a[0] = (short)f2bf(lo.x); a[1] = (short)f2bf(lo.y);
            a[2] = (short)f2bf(lo.z); a[3] = (short)f2bf(lo.w);
            a[4] = (short)f2bf(hi.x); a[5] = (short)f2bf(hi.y);
            a[6] = (short)f2bf(hi.z); a[7] = (short)f2bf(hi.w);
            afrag[ks] = a;
        }
    }

    bool ok_t = (i > 0), ok_b = (i < HN - 1);
    bool okL = (j0 > 0), okR = (j0 + 64 < WN);
    float mt = ok_t ? 1.f : 0.f, mb = ok_b ? 1.f : 0.f;
    int rT = ok_t ? i - 1 : i;
    int rB = ok_b ? i + 1 : i;
    int jL = okL ? j0 - 1 : j0;
    int jR = okR ? j0 + 64 : j0;
    float mLt = okL ? mt : 0.f, mLm = okL ? 1.f : 0.f, mLb = okL ? mb : 0.f;
    float mRt = okR ? mt : 0.f, mRm = okR ? 1.f : 0.f, mRb = okR ? mb : 0.f;
    bool isL = (lane == 0), isR = (lane == 63);

    const float* xb = x + (size_t)b * CN * HW;
    size_t oT = (size_t)rT * WN, oM = (size_t)i * WN, oB = (size_t)rB * WN;
    int j = j0 + lane;

    unsigned short* brow = Bs + lane * KPAD;
#pragma unroll 2
    for (int cp = 0; cp < 8; ++cp) {
        int c0 = (w << 4) + (cp << 1);
        float m0, sx0, sy0, m1, sx1, sy1;
        sobel_col(xb + (size_t)c0 * HW, oT, oM, oB, j, jL, jR,
                  mt, mb, mLt, mLm, mLb, mRt, mRm, mRb, isL, isR, m0, sx0, sy0);
        sobel_col(xb + (size_t)(c0 + 1) * HW, oT, oM, oB, j, jL, jR,
                  mt, mb, mLt, mLm, mLb, mRt, mRm, mRb, isL, isR, m1, sx1, sy1);
        *(unsigned int*)(brow + c0)       = (unsigned int)f2bf(m0)  | ((unsigned int)f2bf(m1)  << 16);
        *(unsigned int*)(brow + 64 + c0)  = (unsigned int)f2bf(sx0) | ((unsigned int)f2bf(sx1) << 16);
        *(unsigned int*)(brow + 128 + c0) = (unsigned int)f2bf(sy0) | ((unsigned int)f2bf(sy1) << 16);
    }

    __syncthreads();

    f32x4 acc[4] = {};
    const unsigned short* bp = Bs + (lane & 15) * KPAD + ((lane >> 4) << 3);
#pragma unroll
    for (int nt = 0; nt < 4; ++nt) {
        const unsigned short* bnt = bp + nt * 16 * KPAD;
#pragma unroll
        for (int ks = 0; ks < 6; ++ks) {
            bf16x8 bf = *(const bf16x8*)(bnt + ks * 32);
            acc[nt] = __builtin_amdgcn_mfma_f32_16x16x32_bf16(afrag[ks], bf, acc[nt], 0, 0, 0);
        }
    }

    int n0 = j0 + (lane & 15);
    int mbase = (w << 4) + ((lane >> 4) << 2);
    size_t outb = (size_t)b * CN * HW + (size_t)i * WN;
#pragma unroll
    for (int rr = 0; rr < 4; ++rr) {
        int m = mbase + rr;
        float bias = bcv[m];
        size_t rowb = outb + (size_t)m * HW + n0;
#pragma unroll
        for (int nt = 0; nt < 4; ++nt)
            feat[rowb + nt * 16] = acc[nt][rr] + bias;
    }
}

// ---------------------------------------------------------------------------
// MLP helper: one wave, lane = hidden unit. Returns head partial sums p[6].
// ---------------------------------------------------------------------------
__device__ inline void run_mlp(int lane, float in0, float in1, float chv, float cwv,
    const float* __restrict__ wb1, const float* __restrict__ bb1,
    const float* __restrict__ wb2, const float* __restrict__ bb2,
    const float* __restrict__ wr,  const float* __restrict__ wo, float p[6])
{
    float4 w1 = ((const float4*)wb1)[lane];
    float h1 = fmaxf(bb1[lane] + w1.x * in0 + w1.y * in1 + w1.z * chv + w1.w * cwv, 0.f);
    const float4* w2row = (const float4*)(wb2 + lane * 64);
    float acc = bb2[lane];
#pragma unroll
    for (int q = 0; q < 16; ++q) {
        float4 wv = w2row[q];
        acc += wv.x * __shfl(h1, q * 4 + 0)
             + wv.y * __shfl(h1, q * 4 + 1)
             + wv.z * __shfl(h1, q * 4 + 2)
             + wv.w * __shfl(h1, q * 4 + 3);
    }
    float h2 = fmaxf(acc, 0.f);
#pragma unroll
    for (int e = 0; e < 4; ++e) p[e] = wr[e * 64 + lane] * h2;
#pragma unroll
    for (int e = 0; e < 2; ++e) p[4 + e] = wo[e * 64 + lane] * h2;
#pragma unroll
    for (int m = 1; m < 64; m <<= 1) {
#pragma unroll
        for (int e = 0; e < 6; ++e) p[e] += __shfl_xor(p[e], m);
    }
}

// ---------------------------------------------------------------------------
// Kernel 2 (v5): routing/offset table + fused expert matrices.
// Fast mode (sc2==2, sc<=16): block pi computes both pj parity classes and
// materializes M = We_mix @ Wc_mix (64x64 per class) as (avg,diff) bf16 at
// tblM[pi][2][64][64]. out_kernel then does out = fea0 + (Mavg+sgn*Mdiff)@fea0
// as a single MFMA GEMM pair. Generic path unchanged.
// ---------------------------------------------------------------------------
__global__ __launch_bounds__(256) void mlp_table_kernel(
    const float* __restrict__ wb1, const float* __restrict__ bb1,
    const float* __restrict__ wb2, const float* __restrict__ bb2,
    const float* __restrict__ wr,  const float* __restrict__ br,
    const float* __restrict__ wo,  const float* __restrict__ bo,
    const float* __restrict__ wce, const float* __restrict__ wee,
    const int* __restrict__ scale_p, const int* __restrict__ scale2_p,
    float* __restrict__ tblEntry, unsigned short* __restrict__ tblM)
{
    __shared__ float reL[8];
    __shared__ float wcmL[2 * 512];   // [parity][k*64+ci]
    __shared__ float wemL[2 * 512];   // [parity][co*8+k]

    int sc = scale_p[0], sc2 = scale2_p[0];
    int tid = threadIdx.x;
    int lane = tid & 63;
    float scale = (float)sc, scale2 = (float)sc2;
    float in0 = 1.f / scale2, in1 = 1.f / scale;
    bool fast = (sc2 == 2 && sc <= 16);

    if (fast) {
        int pi = blockIdx.x;
        if (pi >= sc) return;
        if (tid < 64) {
            float ih = (pi + 0.5f) / scale;
            float chv = ih - floorf(ih + 0.001f) - 0.5f;
            float p0[6], p1[6];
            {
                float iw = 0.5f / scale2;
                float cwv = iw - floorf(iw + 0.001f) - 0.5f;
                run_mlp(lane, in0, in1, chv, cwv, wb1, bb1, wb2, bb2, wr, wo, p0);
            }
            {
                float iw = 1.5f / scale2;
                float cwv = iw - floorf(iw + 0.001f) - 0.5f;
                run_mlp(lane, in0, in1, chv, cwv, wb1, bb1, wb2, bb2, wr, wo, p1);
            }
            if (lane == 0) {
                float* t0 = tblEntry + (pi * 2 + 0) * 8;
                float* t1 = tblEntry + (pi * 2 + 1) * 8;
#pragma unroll
                for (int e = 0; e < 4; ++e) {
                    float rE = 1.f / (1.f + expf(-(p0[e] + br[e])));
                    float rO = 1.f / (1.f + expf(-(p1[e] + br[e])));
                    t0[e] = rE; t1[e] = rO;
                    reL[e] = rE; reL[4 + e] = rO;
                }
                t0[4] = p0[4] + bo[0]; t0[5] = p0[5] + bo[1];
                t1[4] = p1[4] + bo[0]; t1[5] = p1[5] + bo[1];
            }
        }
        __syncthreads();
        float reE0 = reL[0], reE1 = reL[1], reE2 = reL[2], reE3 = reL[3];
        float reO0 = reL[4], reO1 = reL[5], reO2 = reL[6], reO3 = reL[7];
        for (int idx = tid; idx < 512; idx += 256) {
            float a = wce[idx], bq = wce[512 + idx], c = wce[1024 + idx], d = wce[1536 + idx];
            wcmL[idx]       = reE0 * a + reE1 * bq + reE2 * c + reE3 * d;
            wcmL[512 + idx] = reO0 * a + reO1 * bq + reO2 * c + reO3 * d;
            float e_ = wee[idx], f = wee[512 + idx], g = wee[1024 + idx], h = wee[1536 + idx];
            wemL[idx]       = reE0 * e_ + reE1 * f + reE2 * g + reE3 * h;
            wemL[512 + idx] = reO0 * e_ + reO1 * f + reO2 * g + reO3 * h;
        }
        __syncthreads();
        // M[p][co][ci] = sum_k wem[p][co*8+k] * wcm[p][k*64+ci]
        int co  = tid >> 2;
        int ci0 = (tid & 3) << 4;
        float w0[8], w1[8];
#pragma unroll
        for (int k = 0; k < 8; ++k) {
            w0[k] = wemL[co * 8 + k];
            w1[k] = wemL[512 + co * 8 + k];
        }
        unsigned short* tb = tblM + (size_t)pi * 2 * 4096;
#pragma unroll
        for (int cc = 0; cc < 16; ++cc) {
            int ci = ci0 + cc;
            float m0 = 0.f, m1 = 0.f;
#pragma unroll
            for (int k = 0; k < 8; ++k) {
                m0 += w0[k] * wcmL[k * 64 + ci];
                m1 += w1[k] * wcmL[512 + k * 64 + ci];
            }
            tb[co * 64 + ci]        = f2bf(0.5f * (m0 + m1));   // Mavg
            tb[4096 + co * 64 + ci] = f2bf(0.5f * (m0 - m1));   // Mdiff
        }
    } else {
        int w = (blockIdx.x * 256 + threadIdx.x) >> 6;
        if (w >= sc * sc2) return;
        int pi = w / sc2, pj = w - pi * sc2;
        float ih = (pi + 0.5f) / scale;
        float chv = ih - floorf(ih + 0.001f) - 0.5f;
        float iw = (pj + 0.5f) / scale2;
        float cwv = iw - floorf(iw + 0.001f) - 0.5f;
        float p[6];
        run_mlp(lane, in0, in1, chv, cwv, wb1, bb1, wb2, bb2, wr, wo, p);
        if (lane == 0) {
            float* tp = tblEntry + w * 8;
#pragma unroll
            for (int e = 0; e < 4; ++e) tp[e] = 1.f / (1.f + expf(-(p[e] + br[e])));
            tp[4] = p[4] + bo[0];
            tp[5] = p[5] + bo[1];
        }
    }
}

// ---------------------------------------------------------------------------
// Kernel 3 (v4): bilinear gather + fused expert GEMM + residual.
// Block = 64 px row segment x 4 waves (wave = 16 channels for the gather,
// 16 out-channels for the GEMM). Fast path: stage fea0 to LDS (bf16 for MFMA
// B-operand, fp32 for exact residual), then per wave 16 x mfma_16x16x32_bf16
// computing D1 = Mavg@fea0, D2 = Mdiff@fea0; out = fea0 + D1 + sgn*D2.
// Replaces 512 VALU FMAs/lane + midp reduce + 2nd barrier. Generic path kept.
// ---------------------------------------------------------------------------
#define BKP 72   // ushort stride of Bs rows: multiple of 8 -> 16B-aligned b128
__global__ __launch_bounds__(256) void out_kernel(
    const float* __restrict__ feat,      // [B,64,H,W]
    const float* __restrict__ tblEntry,  // [256][8]
    const unsigned short* __restrict__ tblM,  // [pi][2][64][64] bf16
    const float* __restrict__ wce,       // [4,8,64]
    const float* __restrict__ wee,       // [4,64,8]
    const int* __restrict__ scale_p, const int* __restrict__ scale2_p,
    float* __restrict__ out)             // [B,64,SH,SW]
{
    __shared__ __attribute__((aligned(16))) float smem[64 * 65 + 64 * (BKP / 2)];
    float* fea32 = smem;                               // [px][65] fp32
    unsigned short* Bsv = (unsigned short*)(smem + 64 * 65);  // [px][BKP] bf16
    float* midp = smem;                                // generic-path alias

    int Bk = blockIdx.x;
    int T = gridDim.x;                           // 4608, %8==0
    int t = ((T & 7) == 0) ? ((Bk & 7) * (T >> 3) + (Bk >> 3)) : Bk;

    int tid = threadIdx.x;
    int g = __builtin_amdgcn_readfirstlane(tid >> 6);
    int lane = tid & 63;
    int pix0 = t * 64;
    int b = pix0 / (SH * SW);
    int r0 = pix0 - b * SH * SW;
    int i = r0 / SW;
    int j0 = r0 - i * SW;
    int j = j0 + lane;
    int r = r0 + lane;

    int sc = scale_p[0], sc2 = scale2_p[0];
    float scale = (float)sc, scale2 = (float)sc2;
    int pi = i - (i / sc) * sc;          // wave-uniform
    int pj = j - (j / sc2) * sc2;        // per-lane
    int entry = pi * sc2 + pj;
    float offx = tblEntry[entry * 8 + 4];
    float offy = tblEntry[entry * 8 + 5];

    const float inv_wm1 = 2.f / (float)(WN - 1);
    const float inv_hm1 = 2.f / (float)(HN - 1);
    float gx = ((j + 0.5f) / scale2 - 0.5f) * inv_wm1 - 1.f + offx * inv_wm1;
    float gy = ((i + 0.5f) / scale  - 0.5f) * inv_hm1 - 1.f + offy * inv_hm1;

    float ix = ((gx + 1.f) * WN - 1.f) * 0.5f;
    float iy = ((gy + 1.f) * HN - 1.f) * 0.5f;
    float fx0 = floorf(ix), fy0 = floorf(iy);
    int x0 = (int)fx0, y0 = (int)fy0;
    float wx1 = ix - fx0, wx0 = 1.f - wx1;
    float wy1 = iy - fy0, wy0 = 1.f - wy1;

    bool vx0 = (x0 >= 0) && (x0 <= WN - 1);
    bool vx1 = (x0 + 1 >= 0) && (x0 + 1 <= WN - 1);
    bool vy0 = (y0 >= 0) && (y0 <= HN - 1);
    bool vy1 = (y0 + 1 >= 0) && (y0 + 1 <= HN - 1);
    bool v00 = vx0 && vy0, v10 = vx1 && vy0, v01 = vx0 && vy1, v11 = vx1 && vy1;
    float w00 = wx0 * wy0, w10 = wx1 * wy0, w01 = wx0 * wy1, w11 = wx1 * wy1;

    int i00 = y0 * WN + x0;
    int i10 = i00 + 1;
    int i01 = i00 + WN;
    int i11 = i01 + 1;

    const float* fb = feat + (size_t)b * CN * HW;

    float f0[16];
#pragma unroll
    for (int cc = 0; cc < 16; ++cc) {
        const float* fc = fb + (size_t)(g * 16 + cc) * HW;
        float a  = v00 ? fc[i00] : 0.f;
        float bq = v10 ? fc[i10] : 0.f;
        float cq = v01 ? fc[i01] : 0.f;
        float dq = v11 ? fc[i11] : 0.f;
        f0[cc] = a * w00 + bq * w10 + cq * w01 + dq * w11;
    }

    bool fast = (sc2 == 2 && sc <= 16);
    if (fast) {
        // ---- stage fea0: fp32 [px][65] + bf16 [px][BKP] ----
        int px = lane;
#pragma unroll
        for (int cc = 0; cc < 16; ++cc)
            fea32[px * 65 + g * 16 + cc] = f0[cc];
#pragma unroll
        for (int cc = 0; cc < 16; cc += 2) {
            unsigned int pk = (unsigned int)f2bf(f0[cc]) | ((unsigned int)f2bf(f0[cc + 1]) << 16);
            *(unsigned int*)(Bsv + px * BKP + g * 16 + cc) = pk;
        }

        // ---- A fragments (global, issue before barrier): Mavg/Mdiff rows ----
        int row = lane & 15;
        int kb  = (lane >> 4) << 3;
        const unsigned short* Mb = tblM + (size_t)pi * 2 * 4096 + (g * 16 + row) * 64 + kb;
        bf16x8 a1[2], a2[2];
        a1[0] = *(const bf16x8*)(Mb);
        a1[1] = *(const bf16x8*)(Mb + 32);
        a2[0] = *(const bf16x8*)(Mb + 4096);
        a2[1] = *(const bf16x8*)(Mb + 4096 + 32);

        __syncthreads();

        // ---- MFMA: D1 = Mavg@fea0, D2 = Mdiff@fea0 (M=16/wave, N=64, K=64) ----
        f32x4 acc1[4] = {}, acc2[4] = {};
        const unsigned short* bp = Bsv + (lane & 15) * BKP + kb;
#pragma unroll
        for (int nt = 0; nt < 4; ++nt) {
            const unsigned short* bnt = bp + nt * 16 * BKP;
#pragma unroll
            for (int ks = 0; ks < 2; ++ks) {
                bf16x8 bf = *(const bf16x8*)(bnt + ks * 32);
                acc1[nt] = __builtin_amdgcn_mfma_f32_16x16x32_bf16(a1[ks], bf, acc1[nt], 0, 0, 0);
                acc2[nt] = __builtin_amdgcn_mfma_f32_16x16x32_bf16(a2[ks], bf, acc2[nt], 0, 0, 0);
            }
        }

        // ---- epilogue: residual (fp32 LDS) + parity sign, store ----
        int q = lane >> 4;
#pragma unroll
        for (int rr = 0; rr < 4; ++rr) {
            int c = g * 16 + q * 4 + rr;
            size_t rowb = (size_t)(b * CN + c) * SH * SW + r0;
#pragma unroll
            for (int nt = 0; nt < 4; ++nt) {
                int n = (lane & 15) + nt * 16;
                float sgn = (n & 1) ? -1.f : 1.f;
                float v = fea32[n * 65 + c] + acc1[nt][rr] + sgn * acc2[nt][rr];
                out[rowb + n] = v;
            }
        }
    } else {
        float4 rw = *(const float4*)(tblEntry + entry * 8);
        float re[4] = {rw.x, rw.y, rw.z, rw.w};
        float part[4][8];
#pragma unroll
        for (int e = 0; e < 4; ++e) {
#pragma unroll
            for (int k = 0; k < 8; ++k) {
                const float* wrow = wce + (e * 8 + k) * 64 + g * 16;
                float d = 0.f;
#pragma unroll
                for (int cc = 0; cc < 16; ++cc) d += wrow[cc] * f0[cc];
                part[e][k] = d;
            }
        }
#pragma unroll
        for (int k = 0; k < 8; ++k) {
            float m = re[0] * part[0][k] + re[1] * part[1][k]
                    + re[2] * part[2][k] + re[3] * part[3][k];
            midp[(g * 64 + lane) * 9 + k] = m;
        }
        __syncthreads();
        float mid[8];
#pragma unroll
        for (int k = 0; k < 8; ++k)
            mid[k] = midp[(0 * 64 + lane) * 9 + k] + midp[(1 * 64 + lane) * 9 + k]
                   + midp[(2 * 64 + lane) * 9 + k] + midp[(3 * 64 + lane) * 9 + k];
#pragma unroll
        for (int cc = 0; cc < 16; ++cc) {
            int c = g * 16 + cc;
            float v = f0[cc];
#pragma unroll
            for (int e = 0; e < 4; ++e) {
                const float* wrow = wee + (e * 64 + c) * 8;
                float d = 0.f;
#pragma unroll
                for (int k = 0; k < 8; ++k) d += wrow[k] * mid[k];
                v += re[e] * d;
            }
            out[(size_t)(b * CN + c) * SH * SW + r] = v;
        }
    }
}

extern "C" void kernel_launch(void* const* d_in, const int* in_sizes, int n_in,
                              void* d_out, int out_size, void* d_ws, size_t ws_size,
                              hipStream_t stream) {
    const float* x    = (const float*)d_in[0];
    const float* wce  = (const float*)d_in[1];
    const float* wee  = (const float*)d_in[2];
    const float* wb1  = (const float*)d_in[3];
    const float* bb1  = (const float*)d_in[4];
    const float* wb2  = (const float*)d_in[5];
    const float* bb2  = (const float*)d_in[6];
    const float* wr   = (const float*)d_in[7];
    const float* br   = (const float*)d_in[8];
    const float* wo   = (const float*)d_in[9];
    const float* bo   = (const float*)d_in[10];
    const float* wcv  = (const float*)d_in[11];
    const float* bcv  = (const float*)d_in[12];
    const int*   scale  = (const int*)d_in[13];
    const int*   scale2 = (const int*)d_in[14];
    float* out = (float*)d_out;

    float* feat     = (float*)d_ws;                        // BN*CN*HW floats
    float* tblEntry = feat + (size_t)BN * CN * HW;         // 256*8 floats
    unsigned short* tblM = (unsigned short*)(tblEntry + 256 * 8);  // 16*2*4096 bf16

    feat_kernel<<<BN * HN * 3, 256, 0, stream>>>(x, wcv, bcv, feat);
    mlp_table_kernel<<<64, 256, 0, stream>>>(wb1, bb1, wb2, bb2, wr, br, wo, bo,
                                             wce, wee, scale, scale2,
                                             tblEntry, tblM);
    out_kernel<<<BN * SH * SW / 64, 256, 0, stream>>>(feat, tblEntry, tblM,
                                                      wce, wee, scale, scale2, out);
}

// Round 3
// 150.587 us; speedup vs baseline: 1.3286x; 1.0768x over previous
//
#include <hip/hip_runtime.h>
#include <hip/hip_bf16.h>
#include <math.h>

// Problem shape (fixed by setup_inputs):
//   x: [2, 64, 192, 192] fp32, scale=scale2=2 -> sh=sw=384, out: [2,64,384,384] fp32
#define BN  2
#define CN  64
#define HN  192
#define WN  192
#define SH  384
#define SW  384
#define HW  (HN * WN)
#define NPIX (BN * HN * WN)   // 73728

typedef __attribute__((ext_vector_type(8))) short bf16x8;
typedef __attribute__((ext_vector_type(4))) float f32x4;

#define ROWS  2                       // output rows per feat block
#define CPAD  72                      // ushort stride per (row,col) ch-vector: 144B, 16B-aligned
#define MAINB (BN * (HN / ROWS) * 3)  // 576 feat blocks
#define TBLB  64                      // table blocks appended to feat launch

// exact round-to-nearest-even fp32 -> bf16 bits
__device__ inline unsigned short f2bf(float f) {
    unsigned int u = __float_as_uint(f);
    u += 0x7fffu + ((u >> 16) & 1u);
    return (unsigned short)(u >> 16);
}
__device__ inline unsigned int pkbf(float a, float b) {
    return (unsigned int)f2bf(a) | ((unsigned int)f2bf(b) << 16);
}

// ---------------------------------------------------------------------------
// MLP helper: one wave, lane = hidden unit. Returns head partial sums p[6].
// ---------------------------------------------------------------------------
__device__ inline void run_mlp(int lane, float in0, float in1, float chv, float cwv,
    const float* __restrict__ wb1, const float* __restrict__ bb1,
    const float* __restrict__ wb2, const float* __restrict__ bb2,
    const float* __restrict__ wr,  const float* __restrict__ wo, float p[6])
{
    float4 w1 = ((const float4*)wb1)[lane];
    float h1 = fmaxf(bb1[lane] + w1.x * in0 + w1.y * in1 + w1.z * chv + w1.w * cwv, 0.f);
    const float4* w2row = (const float4*)(wb2 + lane * 64);
    float acc = bb2[lane];
#pragma unroll
    for (int q = 0; q < 16; ++q) {
        float4 wv = w2row[q];
        acc += wv.x * __shfl(h1, q * 4 + 0)
             + wv.y * __shfl(h1, q * 4 + 1)
             + wv.z * __shfl(h1, q * 4 + 2)
             + wv.w * __shfl(h1, q * 4 + 3);
    }
    float h2 = fmaxf(acc, 0.f);
#pragma unroll
    for (int e = 0; e < 4; ++e) p[e] = wr[e * 64 + lane] * h2;
#pragma unroll
    for (int e = 0; e < 2; ++e) p[4 + e] = wo[e * 64 + lane] * h2;
#pragma unroll
    for (int m = 1; m < 64; m <<= 1) {
#pragma unroll
        for (int e = 0; e < 6; ++e) p[e] += __shfl_xor(p[e], m);
    }
}

// ---------------------------------------------------------------------------
// Kernel 1 (v7): feat as a dense 3x3-conv MFMA GEMM (sobel folded into taps)
//   feat[o](i,j) = sum_t sum_c W_t[o,c] * x[c](i+dy, j+dx), zero-padded,
//   W_t = w0*delta(center) + w1*KX[t] + w2*KY[t]  (correlation, == shuffle sobel).
// Block = 2 out rows x 64 cols x all 64 out-ch (4 waves, wave = 16 out-ch).
// Stage: raw x tile (4 rows x 66 cols x 64 ch) -> bf16 LDS [4][66][CPAD].
//   Wave w stages row w: 16 iters x 4 coalesced ch-plane loads -> ds_write_b64.
// A: per-tap weight fragments built in-registers from wcv (no precompute dep).
// Compute: 2ro x 4nt x 9t x 2kc = 144 x mfma_16x16x32_bf16; all ds_read_b128
//   from ONE base VGPR + immediate offsets (CPAD=72 -> even bank spread).
// Tail blocks (blockIdx >= MAINB): routing/offset table (v5 logic, LDS aliased).
// ---------------------------------------------------------------------------
__global__ __launch_bounds__(256) void feat_table_kernel(
    const float* __restrict__ x,     // [B,64,H,W]
    const float* __restrict__ wcv,   // [64,192]
    const float* __restrict__ bcv,   // [64]
    float* __restrict__ feat,        // [B,64,H,W]
    const float* __restrict__ wb1, const float* __restrict__ bb1,
    const float* __restrict__ wb2, const float* __restrict__ bb2,
    const float* __restrict__ wr,  const float* __restrict__ br,
    const float* __restrict__ wo,  const float* __restrict__ bo,
    const float* __restrict__ wce, const float* __restrict__ wee,
    const int* __restrict__ scale_p, const int* __restrict__ scale2_p,
    float* __restrict__ tblEntry, unsigned short* __restrict__ tblM)
{
    __shared__ __attribute__((aligned(16))) unsigned short smem_u16[4 * 66 * CPAD]; // 38016 B

    int tid  = threadIdx.x;
    int lane = tid & 63;

    if (blockIdx.x >= MAINB) {
        // ================= table path (LDS aliased onto smem_u16) =========
        float* wcmL = (float*)smem_u16;        // [2][512]
        float* wemL = wcmL + 1024;             // [2][512]
        float* reL  = wemL + 1024;             // [8]

        int sc = scale_p[0], sc2 = scale2_p[0];
        float scale = (float)sc, scale2 = (float)sc2;
        float in0 = 1.f / scale2, in1 = 1.f / scale;
        bool fast = (sc2 == 2 && sc <= 16);
        int tb = blockIdx.x - MAINB;

        if (fast) {
            int pi = tb;
            if (pi >= sc) return;
            if (tid < 64) {
                float ih = (pi + 0.5f) / scale;
                float chv = ih - floorf(ih + 0.001f) - 0.5f;
                float p0[6], p1[6];
                {
                    float iw = 0.5f / scale2;
                    float cwv = iw - floorf(iw + 0.001f) - 0.5f;
                    run_mlp(lane, in0, in1, chv, cwv, wb1, bb1, wb2, bb2, wr, wo, p0);
                }
                {
                    float iw = 1.5f / scale2;
                    float cwv = iw - floorf(iw + 0.001f) - 0.5f;
                    run_mlp(lane, in0, in1, chv, cwv, wb1, bb1, wb2, bb2, wr, wo, p1);
                }
                if (lane == 0) {
                    float* t0 = tblEntry + (pi * 2 + 0) * 8;
                    float* t1 = tblEntry + (pi * 2 + 1) * 8;
#pragma unroll
                    for (int e = 0; e < 4; ++e) {
                        float rE = 1.f / (1.f + expf(-(p0[e] + br[e])));
                        float rO = 1.f / (1.f + expf(-(p1[e] + br[e])));
                        t0[e] = rE; t1[e] = rO;
                        reL[e] = rE; reL[4 + e] = rO;
                    }
                    t0[4] = p0[4] + bo[0]; t0[5] = p0[5] + bo[1];
                    t1[4] = p1[4] + bo[0]; t1[5] = p1[5] + bo[1];
                }
            }
            __syncthreads();
            float reE0 = reL[0], reE1 = reL[1], reE2 = reL[2], reE3 = reL[3];
            float reO0 = reL[4], reO1 = reL[5], reO2 = reL[6], reO3 = reL[7];
            for (int idx = tid; idx < 512; idx += 256) {
                float a = wce[idx], bq = wce[512 + idx], c = wce[1024 + idx], d = wce[1536 + idx];
                wcmL[idx]       = reE0 * a + reE1 * bq + reE2 * c + reE3 * d;
                wcmL[512 + idx] = reO0 * a + reO1 * bq + reO2 * c + reO3 * d;
                float e_ = wee[idx], f = wee[512 + idx], g = wee[1024 + idx], h = wee[1536 + idx];
                wemL[idx]       = reE0 * e_ + reE1 * f + reE2 * g + reE3 * h;
                wemL[512 + idx] = reO0 * e_ + reO1 * f + reO2 * g + reO3 * h;
            }
            __syncthreads();
            // M[p][co][ci] = sum_k wem[p][co*8+k] * wcm[p][k*64+ci]
            int co  = tid >> 2;
            int ci0 = (tid & 3) << 4;
            float w0[8], w1[8];
#pragma unroll
            for (int k = 0; k < 8; ++k) {
                w0[k] = wemL[co * 8 + k];
                w1[k] = wemL[512 + co * 8 + k];
            }
            unsigned short* tbp = tblM + (size_t)pi * 2 * 4096;
#pragma unroll
            for (int cc = 0; cc < 16; ++cc) {
                int ci = ci0 + cc;
                float m0 = 0.f, m1 = 0.f;
#pragma unroll
                for (int k = 0; k < 8; ++k) {
                    m0 += w0[k] * wcmL[k * 64 + ci];
                    m1 += w1[k] * wcmL[512 + k * 64 + ci];
                }
                tbp[co * 64 + ci]        = f2bf(0.5f * (m0 + m1));   // Mavg
                tbp[4096 + co * 64 + ci] = f2bf(0.5f * (m0 - m1));   // Mdiff
            }
        } else {
            int w_ = (tb * 256 + tid) >> 6;
            if (w_ >= sc * sc2) return;
            int pi = w_ / sc2, pj = w_ - pi * sc2;
            float ih = (pi + 0.5f) / scale;
            float chv = ih - floorf(ih + 0.001f) - 0.5f;
            float iw = (pj + 0.5f) / scale2;
            float cwv = iw - floorf(iw + 0.001f) - 0.5f;
            float p[6];
            run_mlp(lane, in0, in1, chv, cwv, wb1, bb1, wb2, bb2, wr, wo, p);
            if (lane == 0) {
                float* tp = tblEntry + w_ * 8;
#pragma unroll
                for (int e = 0; e < 4; ++e) tp[e] = 1.f / (1.f + expf(-(p[e] + br[e])));
                tp[4] = p[4] + bo[0];
                tp[5] = p[5] + bo[1];
            }
        }
        return;
    }

    // ==================== main path: feat 3x3-conv GEMM ====================
    int bi = blockIdx.x;
    int jt = bi % 3;
    int t2 = bi / 3;
    int it = t2 % (HN / ROWS);
    int b  = t2 / (HN / ROWS);
    int i0 = it * ROWS;
    int j0 = jt * 64;
    int w  = __builtin_amdgcn_readfirstlane(tid >> 6);   // wave 0..3

    int row = lane & 15;
    int q   = lane >> 4;

    // ---- A fragments: W_t[o][c] built in-registers from wcv ----
    // tap t = (a,dxi): a = dy+1 = t/3, dxi = dx+1 = t%3
    const float KXc[9] = {-1.f, 0.f, 1.f, -2.f, 0.f, 2.f, -1.f, 0.f, 1.f};
    const float KYc[9] = {-1.f, -2.f, -1.f, 0.f, 0.f, 0.f, 1.f, 2.f, 1.f};
    bf16x8 afrag[9][2];
    {
        int o = (w << 4) + row;
        const float* wp = wcv + o * 192;
        float v0[2][8], v1[2][8], v2[2][8];
#pragma unroll
        for (int kc = 0; kc < 2; ++kc) {
            int kb = kc * 32 + q * 8;
            float4 a0 = *(const float4*)(wp + kb);
            float4 a1 = *(const float4*)(wp + kb + 4);
            float4 b0 = *(const float4*)(wp + 64 + kb);
            float4 b1 = *(const float4*)(wp + 64 + kb + 4);
            float4 c0 = *(const float4*)(wp + 128 + kb);
            float4 c1 = *(const float4*)(wp + 128 + kb + 4);
            v0[kc][0]=a0.x; v0[kc][1]=a0.y; v0[kc][2]=a0.z; v0[kc][3]=a0.w;
            v0[kc][4]=a1.x; v0[kc][5]=a1.y; v0[kc][6]=a1.z; v0[kc][7]=a1.w;
            v1[kc][0]=b0.x; v1[kc][1]=b0.y; v1[kc][2]=b0.z; v1[kc][3]=b0.w;
            v1[kc][4]=b1.x; v1[kc][5]=b1.y; v1[kc][6]=b1.z; v1[kc][7]=b1.w;
            v2[kc][0]=c0.x; v2[kc][1]=c0.y; v2[kc][2]=c0.z; v2[kc][3]=c0.w;
            v2[kc][4]=c1.x; v2[kc][5]=c1.y; v2[kc][6]=c1.z; v2[kc][7]=c1.w;
        }
#pragma unroll
        for (int t = 0; t < 9; ++t) {
#pragma unroll
            for (int kc = 0; kc < 2; ++kc) {
                bf16x8 a;
#pragma unroll
                for (int e = 0; e < 8; ++e) {
                    float f = v1[kc][e] * KXc[t] + v2[kc][e] * KYc[t];
                    if (t == 4) f += v0[kc][e];
                    a[e] = (short)f2bf(f);
                }
                afrag[t][kc] = a;
            }
        }
    }

    // ---- stage x tile: wave w stages xs row w (input row i0-1+w) ----
    {
        int sr = i0 - 1 + w;
        bool rok = (sr >= 0) && (sr < HN);
        int src = rok ? sr : 0;
        int hc = j0 - 1 + lane;                 // xs cols 0..63
        bool cok = (hc >= 0) && (hc < WN);
        int hcc = cok ? hc : 0;
        float msk = (rok && cok) ? 1.f : 0.f;
        const float* p = x + (size_t)b * CN * HW + (size_t)src * WN + hcc;
        unsigned short* xrow = smem_u16 + (w * 66 + lane) * CPAD;
#pragma unroll 4
        for (int k = 0; k < 16; ++k) {
            int c0 = k << 2;
            float a0 = p[0] * msk;
            float a1 = p[(size_t)HW] * msk;
            float a2 = p[2 * (size_t)HW] * msk;
            float a3 = p[3 * (size_t)HW] * msk;
            uint2 uu;
            uu.x = pkbf(a0, a1);
            uu.y = pkbf(a2, a3);
            *(uint2*)(xrow + c0) = uu;
            p += 4 * (size_t)HW;
        }
        // xs cols 64,65 (2 halo cols): 32 lanes cover 2 cols x 16 ch-quads
        if (lane < 32) {
            int colx = 64 + (lane & 1);
            int c0 = (lane >> 1) << 2;
            int hx = j0 - 1 + colx;             // j0+63 or j0+64
            bool cokx = (hx < WN);
            int hxc = cokx ? hx : 0;
            float mskx = (rok && cokx) ? 1.f : 0.f;
            const float* px = x + ((size_t)b * CN + c0) * HW + (size_t)src * WN + hxc;
            float a0 = px[0] * mskx;
            float a1 = px[(size_t)HW] * mskx;
            float a2 = px[2 * (size_t)HW] * mskx;
            float a3 = px[3 * (size_t)HW] * mskx;
            uint2 uu;
            uu.x = pkbf(a0, a1);
            uu.y = pkbf(a2, a3);
            *(uint2*)(smem_u16 + (w * 66 + colx) * CPAD + c0) = uu;
        }
    }

    __syncthreads();

    // ---- MFMA: 2 out rows x 4 n-subtiles x 9 taps x 2 k-chunks ----
    f32x4 acc[2][4] = {};
    const unsigned short* bb0 = smem_u16 + row * CPAD + (q << 3);
#pragma unroll
    for (int ro = 0; ro < 2; ++ro) {
#pragma unroll
        for (int nt = 0; nt < 4; ++nt) {
#pragma unroll
            for (int t = 0; t < 9; ++t) {
                int a_ = t / 3, dxi = t - a_ * 3;
#pragma unroll
                for (int kc = 0; kc < 2; ++kc) {
                    bf16x8 bv = *(const bf16x8*)(bb0 + ((ro + a_) * 66 + nt * 16 + dxi) * CPAD + kc * 32);
                    acc[ro][nt] = __builtin_amdgcn_mfma_f32_16x16x32_bf16(afrag[t][kc], bv, acc[ro][nt], 0, 0, 0);
                }
            }
        }
    }

    // ---- epilogue: bias + store (D: col=lane&15, och = q*4+rr) ----
#pragma unroll
    for (int ro = 0; ro < 2; ++ro) {
        size_t rb0 = (size_t)b * CN * HW + (size_t)(i0 + ro) * WN + j0 + row;
#pragma unroll
        for (int rr = 0; rr < 4; ++rr) {
            int oc = (w << 4) + q * 4 + rr;
            float bias = bcv[oc];
            size_t rowb = rb0 + (size_t)oc * HW;
#pragma unroll
            for (int nt = 0; nt < 4; ++nt)
                feat[rowb + nt * 16] = acc[ro][nt][rr] + bias;
        }
    }
}

// ---------------------------------------------------------------------------
// Kernel 2 (v4, unchanged): bilinear gather + fused expert GEMM + residual.
// ---------------------------------------------------------------------------
#define BKP 72   // ushort stride of Bs rows: multiple of 8 -> 16B-aligned b128
__global__ __launch_bounds__(256) void out_kernel(
    const float* __restrict__ feat,      // [B,64,H,W]
    const float* __restrict__ tblEntry,  // [256][8]
    const unsigned short* __restrict__ tblM,  // [pi][2][64][64] bf16
    const float* __restrict__ wce,       // [4,8,64]
    const float* __restrict__ wee,       // [4,64,8]
    const int* __restrict__ scale_p, const int* __restrict__ scale2_p,
    float* __restrict__ out)             // [B,64,SH,SW]
{
    __shared__ __attribute__((aligned(16))) float smem[64 * 65 + 64 * (BKP / 2)];
    float* fea32 = smem;                               // [px][65] fp32
    unsigned short* Bsv = (unsigned short*)(smem + 64 * 65);  // [px][BKP] bf16
    float* midp = smem;                                // generic-path alias

    int Bk = blockIdx.x;
    int T = gridDim.x;                           // 4608, %8==0
    int t = ((T & 7) == 0) ? ((Bk & 7) * (T >> 3) + (Bk >> 3)) : Bk;

    int tid = threadIdx.x;
    int g = __builtin_amdgcn_readfirstlane(tid >> 6);
    int lane = tid & 63;
    int pix0 = t * 64;
    int b = pix0 / (SH * SW);
    int r0 = pix0 - b * SH * SW;
    int i = r0 / SW;
    int j0 = r0 - i * SW;
    int j = j0 + lane;
    int r = r0 + lane;

    int sc = scale_p[0], sc2 = scale2_p[0];
    float scale = (float)sc, scale2 = (float)sc2;
    int pi = i - (i / sc) * sc;          // wave-uniform
    int pj = j - (j / sc2) * sc2;        // per-lane
    int entry = pi * sc2 + pj;
    float offx = tblEntry[entry * 8 + 4];
    float offy = tblEntry[entry * 8 + 5];

    const float inv_wm1 = 2.f / (float)(WN - 1);
    const float inv_hm1 = 2.f / (float)(HN - 1);
    float gx = ((j + 0.5f) / scale2 - 0.5f) * inv_wm1 - 1.f + offx * inv_wm1;
    float gy = ((i + 0.5f) / scale  - 0.5f) * inv_hm1 - 1.f + offy * inv_hm1;

    float ix = ((gx + 1.f) * WN - 1.f) * 0.5f;
    float iy = ((gy + 1.f) * HN - 1.f) * 0.5f;
    float fx0 = floorf(ix), fy0 = floorf(iy);
    int x0 = (int)fx0, y0 = (int)fy0;
    float wx1 = ix - fx0, wx0 = 1.f - wx1;
    float wy1 = iy - fy0, wy0 = 1.f - wy1;

    bool vx0 = (x0 >= 0) && (x0 <= WN - 1);
    bool vx1 = (x0 + 1 >= 0) && (x0 + 1 <= WN - 1);
    bool vy0 = (y0 >= 0) && (y0 <= HN - 1);
    bool vy1 = (y0 + 1 >= 0) && (y0 + 1 <= HN - 1);
    bool v00 = vx0 && vy0, v10 = vx1 && vy0, v01 = vx0 && vy1, v11 = vx1 && vy1;
    float w00 = wx0 * wy0, w10 = wx1 * wy0, w01 = wx0 * wy1, w11 = wx1 * wy1;

    int i00 = y0 * WN + x0;
    int i10 = i00 + 1;
    int i01 = i00 + WN;
    int i11 = i01 + 1;

    const float* fb = feat + (size_t)b * CN * HW;

    float f0[16];
#pragma unroll
    for (int cc = 0; cc < 16; ++cc) {
        const float* fc = fb + (size_t)(g * 16 + cc) * HW;
        float a  = v00 ? fc[i00] : 0.f;
        float bq = v10 ? fc[i10] : 0.f;
        float cq = v01 ? fc[i01] : 0.f;
        float dq = v11 ? fc[i11] : 0.f;
        f0[cc] = a * w00 + bq * w10 + cq * w01 + dq * w11;
    }

    bool fast = (sc2 == 2 && sc <= 16);
    if (fast) {
        // ---- stage fea0: fp32 [px][65] + bf16 [px][BKP] ----
        int px = lane;
#pragma unroll
        for (int cc = 0; cc < 16; ++cc)
            fea32[px * 65 + g * 16 + cc] = f0[cc];
#pragma unroll
        for (int cc = 0; cc < 16; cc += 2) {
            unsigned int pk = (unsigned int)f2bf(f0[cc]) | ((unsigned int)f2bf(f0[cc + 1]) << 16);
            *(unsigned int*)(Bsv + px * BKP + g * 16 + cc) = pk;
        }

        // ---- A fragments (global, issue before barrier): Mavg/Mdiff rows ----
        int row = lane & 15;
        int kb  = (lane >> 4) << 3;
        const unsigned short* Mb = tblM + (size_t)pi * 2 * 4096 + (g * 16 + row) * 64 + kb;
        bf16x8 a1[2], a2[2];
        a1[0] = *(const bf16x8*)(Mb);
        a1[1] = *(const bf16x8*)(Mb + 32);
        a2[0] = *(const bf16x8*)(Mb + 4096);
        a2[1] = *(const bf16x8*)(Mb + 4096 + 32);

        __syncthreads();

        // ---- MFMA: D1 = Mavg@fea0, D2 = Mdiff@fea0 (M=16/wave, N=64, K=64) ----
        f32x4 acc1[4] = {}, acc2[4] = {};
        const unsigned short* bp = Bsv + (lane & 15) * BKP + kb;
#pragma unroll
        for (int nt = 0; nt < 4; ++nt) {
            const unsigned short* bnt = bp + nt * 16 * BKP;
#pragma unroll
            for (int ks = 0; ks < 2; ++ks) {
                bf16x8 bf = *(const bf16x8*)(bnt + ks * 32);
                acc1[nt] = __builtin_amdgcn_mfma_f32_16x16x32_bf16(a1[ks], bf, acc1[nt], 0, 0, 0);
                acc2[nt] = __builtin_amdgcn_mfma_f32_16x16x32_bf16(a2[ks], bf, acc2[nt], 0, 0, 0);
            }
        }

        // ---- epilogue: residual (fp32 LDS) + parity sign, store ----
        int q = lane >> 4;
#pragma unroll
        for (int rr = 0; rr < 4; ++rr) {
            int c = g * 16 + q * 4 + rr;
            size_t rowb = (size_t)(b * CN + c) * SH * SW + r0;
#pragma unroll
            for (int nt = 0; nt < 4; ++nt) {
                int n = (lane & 15) + nt * 16;
                float sgn = (n & 1) ? -1.f : 1.f;
                float v = fea32[n * 65 + c] + acc1[nt][rr] + sgn * acc2[nt][rr];
                out[rowb + n] = v;
            }
        }
    } else {
        float4 rw = *(const float4*)(tblEntry + entry * 8);
        float re[4] = {rw.x, rw.y, rw.z, rw.w};
        float part[4][8];
#pragma unroll
        for (int e = 0; e < 4; ++e) {
#pragma unroll
            for (int k = 0; k < 8; ++k) {
                const float* wrow = wce + (e * 8 + k) * 64 + g * 16;
                float d = 0.f;
#pragma unroll
                for (int cc = 0; cc < 16; ++cc) d += wrow[cc] * f0[cc];
                part[e][k] = d;
            }
        }
#pragma unroll
        for (int k = 0; k < 8; ++k) {
            float m = re[0] * part[0][k] + re[1] * part[1][k]
                    + re[2] * part[2][k] + re[3] * part[3][k];
            midp[(g * 64 + lane) * 9 + k] = m;
        }
        __syncthreads();
        float mid[8];
#pragma unroll
        for (int k = 0; k < 8; ++k)
            mid[k] = midp[(0 * 64 + lane) * 9 + k] + midp[(1 * 64 + lane) * 9 + k]
                   + midp[(2 * 64 + lane) * 9 + k] + midp[(3 * 64 + lane) * 9 + k];
#pragma unroll
        for (int cc = 0; cc < 16; ++cc) {
            int c = g * 16 + cc;
            float v = f0[cc];
#pragma unroll
            for (int e = 0; e < 4; ++e) {
                const float* wrow = wee + (e * 64 + c) * 8;
                float d = 0.f;
#pragma unroll
                for (int k = 0; k < 8; ++k) d += wrow[k] * mid[k];
                v += re[e] * d;
            }
            out[(size_t)(b * CN + c) * SH * SW + r] = v;
        }
    }
}

extern "C" void kernel_launch(void* const* d_in, const int* in_sizes, int n_in,
                              void* d_out, int out_size, void* d_ws, size_t ws_size,
                              hipStream_t stream) {
    const float* x    = (const float*)d_in[0];
    const float* wce  = (const float*)d_in[1];
    const float* wee  = (const float*)d_in[2];
    const float* wb1  = (const float*)d_in[3];
    const float* bb1  = (const float*)d_in[4];
    const float* wb2  = (const float*)d_in[5];
    const float* bb2  = (const float*)d_in[6];
    const float* wr   = (const float*)d_in[7];
    const float* br   = (const float*)d_in[8];
    const float* wo   = (const float*)d_in[9];
    const float* bo   = (const float*)d_in[10];
    const float* wcv  = (const float*)d_in[11];
    const float* bcv  = (const float*)d_in[12];
    const int*   scale  = (const int*)d_in[13];
    const int*   scale2 = (const int*)d_in[14];
    float* out = (float*)d_out;

    float* feat     = (float*)d_ws;                        // BN*CN*HW floats
    float* tblEntry = feat + (size_t)BN * CN * HW;         // 256*8 floats
    unsigned short* tblM = (unsigned short*)(tblEntry + 256 * 8);  // 16*2*4096 bf16

    feat_table_kernel<<<MAINB + TBLB, 256, 0, stream>>>(
        x, wcv, bcv, feat, wb1, bb1, wb2, bb2, wr, br, wo, bo,
        wce, wee, scale, scale2, tblEntry, tblM);
    out_kernel<<<BN * SH * SW / 64, 256, 0, stream>>>(feat, tblEntry, tblM,
                                                      wce, wee, scale, scale2, out);
}